// Round 1
// baseline (456.620 us; speedup 1.0000x reference)
//
#include <hip/hip_runtime.h>

using bf16   = __bf16;
using bf16x4 = __attribute__((ext_vector_type(4))) __bf16;
using bf16x8 = __attribute__((ext_vector_type(8))) __bf16;
using f32x4  = __attribute__((ext_vector_type(4))) float;

#define DEPTH   11
#define NTREES  16
#define DM      256
#define PER     4095      // 2^12 - 1 nodes per tree
#define KDIM    512       // 2*DM
#define NGATES  5

__device__ __forceinline__ float sigf(float x) { return 1.0f / (1.0f + __expf(-x)); }
__device__ __forceinline__ float tanh_fast(float x) {
    float e = __expf(2.0f * x);
    return 1.0f - 2.0f / (e + 1.0f);   // safe at +/-inf
}

// Wt[n][k] = (bf16) W[k][n];  W: [512][1280] f32 row-major -> Wt: [1280][512] bf16
__global__ __launch_bounds__(256) void prep_wt(const float* __restrict__ W,
                                               bf16* __restrict__ Wt) {
    int idx = blockIdx.x * 256 + threadIdx.x;          // 0 .. 512*1280-1
    int kk  = idx / 1280;                               // row of W
    int n   = idx - kk * 1280;                          // col of W (coalesced read)
    Wt[n * KDIM + kk] = (bf16)W[idx];
}

// One wave per leaf: clipped-norm embedding -> acts (f32, = d_out), actsb (bf16), mem=0
__global__ __launch_bounds__(256) void leaf_kernel(const int* __restrict__ tokens,
                                                   const float* __restrict__ emb,
                                                   float* acts, bf16* actsb, float* mem) {
    int wid  = (blockIdx.x * 256 + threadIdx.x) >> 6;   // global leaf index 0..32767
    int lane = threadIdx.x & 63;
    int b    = wid >> 11;
    int loc  = wid & 2047;
    int id   = b * PER + loc;                           // leaf node id (off[0]==0)
    int tok  = tokens[id];

    float4 e = *reinterpret_cast<const float4*>(emb + tok * DM + lane * 4);
    float ss = e.x * e.x + e.y * e.y + e.z * e.z + e.w * e.w;
    #pragma unroll
    for (int off = 32; off; off >>= 1) ss += __shfl_xor(ss, off);
    float scale = fminf(1.0f, 1.0f / fmaxf(sqrtf(ss), 1e-7f));
    e.x *= scale; e.y *= scale; e.z *= scale; e.w *= scale;

    int o = id * DM + lane * 4;
    *reinterpret_cast<float4*>(acts + o) = e;
    bf16x4 eb;
    eb.x = (bf16)e.x; eb.y = (bf16)e.y; eb.z = (bf16)e.z; eb.w = (bf16)e.w;
    *reinterpret_cast<bf16x4*>(actsb + o) = eb;
    *reinterpret_cast<float4*>(mem + o) = make_float4(0.f, 0.f, 0.f, 0.f);
}

// One level: GEMM [M_total x 512] x Wt^T + fused LSTM epilogue.
// Wave = 16 node-rows x 16 unit-dims x 5 gates (5 accumulators, 80 MFMA).
// A-row m: tree b = m>>shift, loc = m&mask; children rows are contiguous
// (base + off_km1 + 2*loc, +1) => X row is 512 contiguous bf16.
__global__ __launch_bounds__(256) void level_kernel(
        const bf16* __restrict__ actsb_in, const bf16* __restrict__ Wt,
        const float* __restrict__ bias, float* mem, float* acts, bf16* actsb_out,
        int off_k, int off_km1, int shift) {
    int wid  = blockIdx.x * 4 + (threadIdx.x >> 6);
    int lane = threadIdx.x & 63;
    int tile = wid >> 4;            // node-row tile (16 rows)
    int uc   = wid & 15;            // unit-dim chunk (16 of 256)
    int m0   = tile << 4;
    int lo   = lane & 15;
    int hi   = lane >> 4;           // 0..3
    int mask = (1 << shift) - 1;

    // A fragment base: row = m0+lo, k-block = hi*8
    int mA   = m0 + lo;
    int rowA = (mA >> shift) * PER + off_km1 + ((mA & mask) << 1);
    const bf16* aptr = actsb_in + rowA * DM + hi * 8;

    // B fragment base: col = gate*256 + uc*16 + lo, k-block = hi*8
    int ucol = (uc << 4) + lo;
    const bf16* bptr = Wt + ucol * KDIM + hi * 8;

    f32x4 acc[NGATES] = {};

    #pragma unroll
    for (int kt = 0; kt < KDIM / 32; ++kt) {
        bf16x8 a = *reinterpret_cast<const bf16x8*>(aptr + kt * 32);
        #pragma unroll
        for (int g = 0; g < NGATES; ++g) {
            bf16x8 bb = *reinterpret_cast<const bf16x8*>(bptr + g * (DM * KDIM) + kt * 32);
            acc[g] = __builtin_amdgcn_mfma_f32_16x16x32_bf16(a, bb, acc[g], 0, 0, 0);
        }
    }

    float bi[NGATES];
    #pragma unroll
    for (int g = 0; g < NGATES; ++g) bi[g] = bias[g * DM + ucol];

    // Epilogue. D layout: col = lane&15 (unit dim), row = hi*4 + r (node row).
    #pragma unroll
    for (int r = 0; r < 4; ++r) {
        int m   = m0 + (hi << 2) + r;
        int tb  = (m >> shift) * PER;
        int loc = m & mask;
        int id  = tb + off_k + loc;
        int ch  = (tb + off_km1 + (loc << 1)) * DM + ucol;
        float cl = mem[ch];
        float cr = mem[ch + DM];
        float gi = acc[0][r] + bi[0];
        float gl = acc[1][r] + bi[1];
        float gr = acc[2][r] + bi[2];
        float go = acc[3][r] + bi[3];
        float gu = acc[4][r] + bi[4];
        float c  = sigf(gi) * tanh_fast(gu) + sigf(gl) * cl + sigf(gr) * cr;
        float h  = sigf(go) * tanh_fast(c);
        int oi = id * DM + ucol;
        acts[oi]      = h;
        mem[oi]       = c;
        actsb_out[oi] = (bf16)h;
    }
}

extern "C" void kernel_launch(void* const* d_in, const int* in_sizes, int n_in,
                              void* d_out, int out_size, void* d_ws, size_t ws_size,
                              hipStream_t stream) {
    (void)in_sizes; (void)n_in; (void)out_size; (void)ws_size;
    const int*   tokens = (const int*)d_in[0];
    const float* emb    = (const float*)d_in[8];
    const float* W      = (const float*)d_in[9];
    const float* bias   = (const float*)d_in[10];
    float* acts = (float*)d_out;

    char* ws = (char*)d_ws;
    bf16*  Wt    = (bf16*)ws;                               // 1,310,720 B
    bf16*  actsb = (bf16*)(ws + 1310720);                   // 33,546,240 B
    float* mem   = (float*)(ws + 1310720 + 33546240);       // 67,092,480 B
    // total ws use: ~97.2 MB

    prep_wt<<<dim3(512 * 1280 / 256), dim3(256), 0, stream>>>(W, Wt);
    leaf_kernel<<<dim3(8192), dim3(256), 0, stream>>>(tokens, emb, acts, actsb, mem);

    int off_km1 = 0;
    for (int k = 1; k <= DEPTH; ++k) {
        int shift   = DEPTH - k;
        int width   = 1 << shift;            // nodes per tree at this level
        int off_k   = off_km1 + (width << 1);
        int M_total = NTREES << shift;       // total nodes this level (>=16, %16==0)
        level_kernel<<<dim3(M_total / 4), dim3(256), 0, stream>>>(
            actsb, Wt, bias, mem, acts, actsb, off_k, off_km1, shift);
        off_km1 = off_k;
    }
}

// Round 2
// 386.738 us; speedup vs baseline: 1.1807x; 1.1807x over previous
//
#include <hip/hip_runtime.h>

using bf16   = __bf16;
using bf16x4 = __attribute__((ext_vector_type(4))) __bf16;
using bf16x8 = __attribute__((ext_vector_type(8))) __bf16;
using f32x4  = __attribute__((ext_vector_type(4))) float;

#define DEPTH   11
#define NTREES  16
#define DM      256
#define PER     4095      // 2^12 - 1 nodes per tree
#define KDIM    512       // 2*DM
#define NGATES  5

__device__ __forceinline__ float sigf(float x) { return 1.0f / (1.0f + __expf(-x)); }
__device__ __forceinline__ float tanh_fast(float x) {
    float e = __expf(2.0f * x);
    return 1.0f - 2.0f / (e + 1.0f);   // safe at +/-inf
}

// Wt[n][k] = (bf16) W[k][n];  W: [512][1280] f32 row-major -> Wt: [1280][512] bf16
__global__ __launch_bounds__(256) void prep_wt(const float* __restrict__ W,
                                               bf16* __restrict__ Wt) {
    int idx = blockIdx.x * 256 + threadIdx.x;          // 0 .. 512*1280-1
    int kk  = idx / 1280;                               // row of W
    int n   = idx - kk * 1280;                          // col of W (coalesced read)
    Wt[n * KDIM + kk] = (bf16)W[idx];
}

// One wave per leaf: clipped-norm embedding -> acts (f32, = d_out), actsb (bf16), mem=0
__global__ __launch_bounds__(256) void leaf_kernel(const int* __restrict__ tokens,
                                                   const float* __restrict__ emb,
                                                   float* acts, bf16* actsb, float* mem) {
    int wid  = (blockIdx.x * 256 + threadIdx.x) >> 6;   // global leaf index 0..32767
    int lane = threadIdx.x & 63;
    int b    = wid >> 11;
    int loc  = wid & 2047;
    int id   = b * PER + loc;                           // leaf node id (off[0]==0)
    int tok  = tokens[id];

    float4 e = *reinterpret_cast<const float4*>(emb + tok * DM + lane * 4);
    float ss = e.x * e.x + e.y * e.y + e.z * e.z + e.w * e.w;
    #pragma unroll
    for (int off = 32; off; off >>= 1) ss += __shfl_xor(ss, off);
    float scale = fminf(1.0f, 1.0f / fmaxf(sqrtf(ss), 1e-7f));
    e.x *= scale; e.y *= scale; e.z *= scale; e.w *= scale;

    int o = id * DM + lane * 4;
    *reinterpret_cast<float4*>(acts + o) = e;
    bf16x4 eb;
    eb.x = (bf16)e.x; eb.y = (bf16)e.y; eb.z = (bf16)e.z; eb.w = (bf16)e.w;
    *reinterpret_cast<bf16x4*>(actsb + o) = eb;
    *reinterpret_cast<float4*>(mem + o) = make_float4(0.f, 0.f, 0.f, 0.f);
}

// ---------- 16-row fallback kernel (small levels, M_total < 64) ----------
__global__ __launch_bounds__(256) void level_kernel(
        const bf16* __restrict__ actsb_in, const bf16* __restrict__ Wt,
        const float* __restrict__ bias, float* mem, float* acts, bf16* actsb_out,
        int off_k, int off_km1, int shift) {
    int wid  = blockIdx.x * 4 + (threadIdx.x >> 6);
    int lane = threadIdx.x & 63;
    int tile = wid >> 4;            // node-row tile (16 rows)
    int uc   = wid & 15;            // unit-dim chunk (16 of 256)
    int m0   = tile << 4;
    int lo   = lane & 15;
    int hi   = lane >> 4;           // 0..3
    int mask = (1 << shift) - 1;

    int mA   = m0 + lo;
    int rowA = (mA >> shift) * PER + off_km1 + ((mA & mask) << 1);
    const bf16* aptr = actsb_in + rowA * DM + hi * 8;

    int ucol = (uc << 4) + lo;
    const bf16* bptr = Wt + ucol * KDIM + hi * 8;

    f32x4 acc[NGATES] = {};

    #pragma unroll
    for (int kt = 0; kt < KDIM / 32; ++kt) {
        bf16x8 a = *reinterpret_cast<const bf16x8*>(aptr + kt * 32);
        #pragma unroll
        for (int g = 0; g < NGATES; ++g) {
            bf16x8 bb = *reinterpret_cast<const bf16x8*>(bptr + g * (DM * KDIM) + kt * 32);
            acc[g] = __builtin_amdgcn_mfma_f32_16x16x32_bf16(a, bb, acc[g], 0, 0, 0);
        }
    }

    float bi[NGATES];
    #pragma unroll
    for (int g = 0; g < NGATES; ++g) bi[g] = bias[g * DM + ucol];

    #pragma unroll
    for (int r = 0; r < 4; ++r) {
        int m   = m0 + (hi << 2) + r;
        int tb  = (m >> shift) * PER;
        int loc = m & mask;
        int id  = tb + off_k + loc;
        int ch  = (tb + off_km1 + (loc << 1)) * DM + ucol;
        float cl = mem[ch];
        float cr = mem[ch + DM];
        float gi = acc[0][r] + bi[0];
        float gl = acc[1][r] + bi[1];
        float gr = acc[2][r] + bi[2];
        float go = acc[3][r] + bi[3];
        float gu = acc[4][r] + bi[4];
        float c  = sigf(gi) * tanh_fast(gu) + sigf(gl) * cl + sigf(gr) * cr;
        float h  = sigf(go) * tanh_fast(c);
        int oi = id * DM + ucol;
        acts[oi]      = h;
        mem[oi]       = c;
        actsb_out[oi] = (bf16)h;
    }
}

// ---------- 64-row register-blocked kernel (M_total >= 64) ----------
// Wave = 64 node-rows x 16 unit-dims x 5 gates: acc[5][4] f32x4 (80 VGPR).
// Per K-step: 4 A loads + 5 B loads -> 20 MFMA.
__global__ __launch_bounds__(256) void level_kernel64(
        const bf16* __restrict__ actsb_in, const bf16* __restrict__ Wt,
        const float* __restrict__ bias, float* mem, float* acts, bf16* actsb_out,
        int off_k, int off_km1, int shift) {
    int wid  = threadIdx.x >> 6;
    int lane = threadIdx.x & 63;
    int tile = blockIdx.x >> 2;                 // 64-row tile index
    int uc   = ((blockIdx.x & 3) << 2) + wid;   // 0..15 unit chunk
    int m0   = tile << 6;
    int lo   = lane & 15;
    int hi   = lane >> 4;                       // 0..3
    int mask = (1 << shift) - 1;

    const bf16* aptr[4];
    #pragma unroll
    for (int rg = 0; rg < 4; ++rg) {
        int mA   = m0 + (rg << 4) + lo;
        int rowA = (mA >> shift) * PER + off_km1 + ((mA & mask) << 1);
        aptr[rg] = actsb_in + rowA * DM + hi * 8;
    }
    int ucol = (uc << 4) + lo;
    const bf16* bptr = Wt + ucol * KDIM + hi * 8;

    f32x4 acc[NGATES][4] = {};

    #pragma unroll
    for (int kt = 0; kt < KDIM / 32; ++kt) {
        bf16x8 a[4];
        #pragma unroll
        for (int rg = 0; rg < 4; ++rg)
            a[rg] = *reinterpret_cast<const bf16x8*>(aptr[rg] + kt * 32);
        #pragma unroll
        for (int g = 0; g < NGATES; ++g) {
            bf16x8 bb = *reinterpret_cast<const bf16x8*>(bptr + g * (DM * KDIM) + kt * 32);
            #pragma unroll
            for (int rg = 0; rg < 4; ++rg)
                acc[g][rg] = __builtin_amdgcn_mfma_f32_16x16x32_bf16(a[rg], bb, acc[g][rg], 0, 0, 0);
        }
    }

    float bi[NGATES];
    #pragma unroll
    for (int g = 0; g < NGATES; ++g) bi[g] = bias[g * DM + ucol];

    #pragma unroll
    for (int rg = 0; rg < 4; ++rg) {
        #pragma unroll
        for (int r = 0; r < 4; ++r) {
            int m   = m0 + (rg << 4) + (hi << 2) + r;
            int tb  = (m >> shift) * PER;
            int loc = m & mask;
            int id  = tb + off_k + loc;
            int ch  = (tb + off_km1 + (loc << 1)) * DM + ucol;
            float cl = mem[ch];
            float cr = mem[ch + DM];
            float gi = acc[0][rg][r] + bi[0];
            float gl = acc[1][rg][r] + bi[1];
            float gr = acc[2][rg][r] + bi[2];
            float go = acc[3][rg][r] + bi[3];
            float gu = acc[4][rg][r] + bi[4];
            float c  = sigf(gi) * tanh_fast(gu) + sigf(gl) * cl + sigf(gr) * cr;
            float h  = sigf(go) * tanh_fast(c);
            int oi = id * DM + ucol;
            acts[oi]      = h;
            mem[oi]       = c;
            actsb_out[oi] = (bf16)h;
        }
    }
}

extern "C" void kernel_launch(void* const* d_in, const int* in_sizes, int n_in,
                              void* d_out, int out_size, void* d_ws, size_t ws_size,
                              hipStream_t stream) {
    (void)in_sizes; (void)n_in; (void)out_size; (void)ws_size;
    const int*   tokens = (const int*)d_in[0];
    const float* emb    = (const float*)d_in[8];
    const float* W      = (const float*)d_in[9];
    const float* bias   = (const float*)d_in[10];
    float* acts = (float*)d_out;

    char* ws = (char*)d_ws;
    bf16*  Wt    = (bf16*)ws;                               // 1,310,720 B
    bf16*  actsb = (bf16*)(ws + 1310720);                   // 33,546,240 B
    float* mem   = (float*)(ws + 1310720 + 33546240);       // 67,092,480 B

    prep_wt<<<dim3(512 * 1280 / 256), dim3(256), 0, stream>>>(W, Wt);
    leaf_kernel<<<dim3(8192), dim3(256), 0, stream>>>(tokens, emb, acts, actsb, mem);

    int off_km1 = 0;
    for (int k = 1; k <= DEPTH; ++k) {
        int shift   = DEPTH - k;
        int width   = 1 << shift;            // nodes per tree at this level
        int off_k   = off_km1 + (width << 1);
        int M_total = NTREES << shift;       // total nodes this level
        if (M_total >= 64) {
            level_kernel64<<<dim3(M_total / 16), dim3(256), 0, stream>>>(
                actsb, Wt, bias, mem, acts, actsb, off_k, off_km1, shift);
        } else {
            level_kernel<<<dim3(M_total / 4), dim3(256), 0, stream>>>(
                actsb, Wt, bias, mem, acts, actsb, off_k, off_km1, shift);
        }
        off_km1 = off_k;
    }
}

// Round 3
// 333.433 us; speedup vs baseline: 1.3694x; 1.1599x over previous
//
#include <hip/hip_runtime.h>
#include <stdint.h>

using bf16   = __bf16;
using bf16x4 = __attribute__((ext_vector_type(4))) __bf16;
using bf16x8 = __attribute__((ext_vector_type(8))) __bf16;
using f32x4  = __attribute__((ext_vector_type(4))) float;

#define DEPTH   11
#define NTREES  16
#define DM      256
#define PER     4095      // 2^12 - 1 nodes per tree
#define KDIM    512       // 2*DM
#define NGATES  5

__device__ __forceinline__ float sigf(float x) { return 1.0f / (1.0f + __expf(-x)); }
__device__ __forceinline__ float tanh_fast(float x) {
    float e = __expf(2.0f * x);
    return 1.0f - 2.0f / (e + 1.0f);   // safe at +/-inf
}

__device__ __forceinline__ void load_lds16(const bf16* g, bf16* l) {
    __builtin_amdgcn_global_load_lds((const __attribute__((address_space(1))) void*)g,
                                     (__attribute__((address_space(3))) void*)l,
                                     16, 0, 0);
}

// Wt[n][k] = (bf16) W[k][n];  W: [512][1280] f32 row-major -> Wt: [1280][512] bf16
__global__ __launch_bounds__(256) void prep_wt(const float* __restrict__ W,
                                               bf16* __restrict__ Wt) {
    int idx = blockIdx.x * 256 + threadIdx.x;          // 0 .. 512*1280-1
    int kk  = idx / 1280;                               // row of W
    int n   = idx - kk * 1280;                          // col of W (coalesced read)
    Wt[n * KDIM + kk] = (bf16)W[idx];
}

// One wave per leaf: clipped-norm embedding -> acts (f32, = d_out), actsb (bf16).
// mem for leaves is NOT written: level 1 uses zmem=1 (children mem == 0).
__global__ __launch_bounds__(256) void leaf_kernel(const int* __restrict__ tokens,
                                                   const float* __restrict__ emb,
                                                   float* acts, bf16* actsb) {
    int wid  = (blockIdx.x * 256 + threadIdx.x) >> 6;   // global leaf index 0..32767
    int lane = threadIdx.x & 63;
    int b    = wid >> 11;
    int loc  = wid & 2047;
    int id   = b * PER + loc;                           // leaf node id (off[0]==0)
    int tok  = tokens[id];

    float4 e = *reinterpret_cast<const float4*>(emb + tok * DM + lane * 4);
    float ss = e.x * e.x + e.y * e.y + e.z * e.z + e.w * e.w;
    #pragma unroll
    for (int off = 32; off; off >>= 1) ss += __shfl_xor(ss, off);
    float scale = fminf(1.0f, 1.0f / fmaxf(sqrtf(ss), 1e-7f));
    e.x *= scale; e.y *= scale; e.z *= scale; e.w *= scale;

    int o = id * DM + lane * 4;
    *reinterpret_cast<float4*>(acts + o) = e;
    bf16x4 eb;
    eb.x = (bf16)e.x; eb.y = (bf16)e.y; eb.z = (bf16)e.z; eb.w = (bf16)e.w;
    *reinterpret_cast<bf16x4*>(actsb + o) = eb;
}

// ---------- LDS-staged big-level kernel (Mt >= 128 rows per tree) ----------
// Block: 256 thr (4 waves, 2x2), output tile 128 rows x (32 ucols x 5 gates).
// LDS: A [kblk8][row128][8] bf16 (16 KB), B [kblk8][col160][8] bf16 (20 KB).
// Staged via global_load_lds(16B): linear LDS dest, per-lane strided source.
// Per K-step(64) per wave: 8+10 ds_read_b128, 40 MFMA; 2-barrier m97 loop.
__global__ __launch_bounds__(256) void level_big(
        const bf16* __restrict__ actsb_in, const bf16* __restrict__ Wt,
        const float* __restrict__ bias, float* __restrict__ mem,
        float* __restrict__ acts, bf16* __restrict__ actsb_out,
        int off_k, int off_km1, int zmem) {
    __shared__ __align__(16) bf16 ldsA[8][128][8];
    __shared__ __align__(16) bf16 ldsB[8][160][8];

    int t    = threadIdx.x;
    int lane = t & 63;
    int w    = t >> 6;
    int lo   = lane & 15;
    int hi   = lane >> 4;          // 0..3
    int wr   = w >> 1;             // row half (64 rows)
    int wu   = w & 1;              // ucol half (16 ucols)

    int rt   = blockIdx.x >> 3;    // row tile (128 rows within tree)
    int uct  = blockIdx.x & 7;     // ucol tile (32 of 256)
    int b    = blockIdx.y;         // tree

    int rm  = rt << 7;
    int uc0 = uct << 5;

    // A is a contiguous [Mt][512] bf16 matrix: row m = children (2m, 2m+1) of
    // level k-1, each 256 wide, adjacent in actsb.
    const bf16* Abase = actsb_in + (size_t)(b * PER + off_km1) * DM;

    // Staging sources. A slot s = i*256+t: row = s&127, kblk = s>>7.
    const bf16* aSrc[4];
    #pragma unroll
    for (int i = 0; i < 4; ++i) {
        int s   = i * 256 + t;
        aSrc[i] = Abase + (size_t)(rm + (s & 127)) * KDIM + (s >> 7) * 8;
    }
    // B slot s = i*256+t: kblk = s/160, col = s%160; col = g*32 + c.
    const bf16* bSrc[5];
    #pragma unroll
    for (int i = 0; i < 5; ++i) {
        int s   = i * 256 + t;
        int kb  = s / 160;
        int col = s - kb * 160;
        int g   = col >> 5;
        int c   = col & 31;
        bSrc[i] = Wt + (size_t)(g * DM + uc0 + c) * KDIM + kb * 8;
    }

    bf16* ldsAf = &ldsA[0][0][0];
    bf16* ldsBf = &ldsB[0][0][0];

    f32x4 acc[NGATES][4] = {};

    for (int kt = 0; kt < 8; ++kt) {
        int ko = kt * 64;
        #pragma unroll
        for (int i = 0; i < 4; ++i)
            load_lds16(aSrc[i] + ko, ldsAf + (i * 256 + t) * 8);
        #pragma unroll
        for (int i = 0; i < 5; ++i)
            load_lds16(bSrc[i] + ko, ldsBf + (i * 256 + t) * 8);
        __syncthreads();   // vmcnt(0) drain + barrier

        #pragma unroll
        for (int q = 0; q < 2; ++q) {
            bf16x8 af[4];
            #pragma unroll
            for (int rg = 0; rg < 4; ++rg)
                af[rg] = *reinterpret_cast<const bf16x8*>(&ldsA[q * 4 + hi][wr * 64 + rg * 16 + lo][0]);
            #pragma unroll
            for (int g = 0; g < NGATES; ++g) {
                bf16x8 bb = *reinterpret_cast<const bf16x8*>(&ldsB[q * 4 + hi][g * 32 + wu * 16 + lo][0]);
                #pragma unroll
                for (int rg = 0; rg < 4; ++rg)
                    acc[g][rg] = __builtin_amdgcn_mfma_f32_16x16x32_bf16(af[rg], bb, acc[g][rg], 0, 0, 0);
            }
        }
        __syncthreads();   // protect LDS before next stage
    }

    int ucol = uc0 + wu * 16 + lo;
    float bi[NGATES];
    #pragma unroll
    for (int g = 0; g < NGATES; ++g) bi[g] = bias[g * DM + ucol];

    int treebase = b * PER;
    #pragma unroll
    for (int rg = 0; rg < 4; ++rg) {
        #pragma unroll
        for (int r = 0; r < 4; ++r) {
            int ml = rm + wr * 64 + rg * 16 + (hi << 2) + r;   // row within tree
            int id = treebase + off_k + ml;
            float cl = 0.0f, cr = 0.0f;
            if (!zmem) {
                int ch = (treebase + off_km1 + (ml << 1)) * DM + ucol;
                cl = mem[ch];
                cr = mem[ch + DM];
            }
            float gi = acc[0][rg][r] + bi[0];
            float gl = acc[1][rg][r] + bi[1];
            float gr = acc[2][rg][r] + bi[2];
            float go = acc[3][rg][r] + bi[3];
            float gu = acc[4][rg][r] + bi[4];
            float c  = sigf(gi) * tanh_fast(gu) + sigf(gl) * cl + sigf(gr) * cr;
            float h  = sigf(go) * tanh_fast(c);
            int oi = id * DM + ucol;
            acts[oi]      = h;
            mem[oi]       = c;
            actsb_out[oi] = (bf16)h;
        }
    }
}

// ---------- 16-row fallback kernel (small levels) ----------
__global__ __launch_bounds__(256) void level_kernel(
        const bf16* __restrict__ actsb_in, const bf16* __restrict__ Wt,
        const float* __restrict__ bias, float* mem, float* acts, bf16* actsb_out,
        int off_k, int off_km1, int shift) {
    int wid  = blockIdx.x * 4 + (threadIdx.x >> 6);
    int lane = threadIdx.x & 63;
    int tile = wid >> 4;
    int uc   = wid & 15;
    int m0   = tile << 4;
    int lo   = lane & 15;
    int hi   = lane >> 4;
    int mask = (1 << shift) - 1;

    int mA   = m0 + lo;
    int rowA = (mA >> shift) * PER + off_km1 + ((mA & mask) << 1);
    const bf16* aptr = actsb_in + rowA * DM + hi * 8;

    int ucol = (uc << 4) + lo;
    const bf16* bptr = Wt + ucol * KDIM + hi * 8;

    f32x4 acc[NGATES] = {};

    #pragma unroll
    for (int kt = 0; kt < KDIM / 32; ++kt) {
        bf16x8 a = *reinterpret_cast<const bf16x8*>(aptr + kt * 32);
        #pragma unroll
        for (int g = 0; g < NGATES; ++g) {
            bf16x8 bb = *reinterpret_cast<const bf16x8*>(bptr + g * (DM * KDIM) + kt * 32);
            acc[g] = __builtin_amdgcn_mfma_f32_16x16x32_bf16(a, bb, acc[g], 0, 0, 0);
        }
    }

    float bi[NGATES];
    #pragma unroll
    for (int g = 0; g < NGATES; ++g) bi[g] = bias[g * DM + ucol];

    #pragma unroll
    for (int r = 0; r < 4; ++r) {
        int m   = m0 + (hi << 2) + r;
        int tb  = (m >> shift) * PER;
        int loc = m & mask;
        int id  = tb + off_k + loc;
        int ch  = (tb + off_km1 + (loc << 1)) * DM + ucol;
        float cl = mem[ch];
        float cr = mem[ch + DM];
        float gi = acc[0][r] + bi[0];
        float gl = acc[1][r] + bi[1];
        float gr = acc[2][r] + bi[2];
        float go = acc[3][r] + bi[3];
        float gu = acc[4][r] + bi[4];
        float c  = sigf(gi) * tanh_fast(gu) + sigf(gl) * cl + sigf(gr) * cr;
        float h  = sigf(go) * tanh_fast(c);
        int oi = id * DM + ucol;
        acts[oi]      = h;
        mem[oi]       = c;
        actsb_out[oi] = (bf16)h;
    }
}

// ---------- 64-row register-blocked kernel (mid levels) ----------
__global__ __launch_bounds__(256) void level_kernel64(
        const bf16* __restrict__ actsb_in, const bf16* __restrict__ Wt,
        const float* __restrict__ bias, float* mem, float* acts, bf16* actsb_out,
        int off_k, int off_km1, int shift) {
    int wid  = threadIdx.x >> 6;
    int lane = threadIdx.x & 63;
    int tile = blockIdx.x >> 2;
    int uc   = ((blockIdx.x & 3) << 2) + wid;
    int m0   = tile << 6;
    int lo   = lane & 15;
    int hi   = lane >> 4;
    int mask = (1 << shift) - 1;

    const bf16* aptr[4];
    #pragma unroll
    for (int rg = 0; rg < 4; ++rg) {
        int mA   = m0 + (rg << 4) + lo;
        int rowA = (mA >> shift) * PER + off_km1 + ((mA & mask) << 1);
        aptr[rg] = actsb_in + rowA * DM + hi * 8;
    }
    int ucol = (uc << 4) + lo;
    const bf16* bptr = Wt + ucol * KDIM + hi * 8;

    f32x4 acc[NGATES][4] = {};

    #pragma unroll
    for (int kt = 0; kt < KDIM / 32; ++kt) {
        bf16x8 a[4];
        #pragma unroll
        for (int rg = 0; rg < 4; ++rg)
            a[rg] = *reinterpret_cast<const bf16x8*>(aptr[rg] + kt * 32);
        #pragma unroll
        for (int g = 0; g < NGATES; ++g) {
            bf16x8 bb = *reinterpret_cast<const bf16x8*>(bptr + g * (DM * KDIM) + kt * 32);
            #pragma unroll
            for (int rg = 0; rg < 4; ++rg)
                acc[g][rg] = __builtin_amdgcn_mfma_f32_16x16x32_bf16(a[rg], bb, acc[g][rg], 0, 0, 0);
        }
    }

    float bi[NGATES];
    #pragma unroll
    for (int g = 0; g < NGATES; ++g) bi[g] = bias[g * DM + ucol];

    #pragma unroll
    for (int rg = 0; rg < 4; ++rg) {
        #pragma unroll
        for (int r = 0; r < 4; ++r) {
            int m   = m0 + (rg << 4) + (hi << 2) + r;
            int tb  = (m >> shift) * PER;
            int loc = m & mask;
            int id  = tb + off_k + loc;
            int ch  = (tb + off_km1 + (loc << 1)) * DM + ucol;
            float cl = mem[ch];
            float cr = mem[ch + DM];
            float gi = acc[0][rg][r] + bi[0];
            float gl = acc[1][rg][r] + bi[1];
            float gr = acc[2][rg][r] + bi[2];
            float go = acc[3][rg][r] + bi[3];
            float gu = acc[4][rg][r] + bi[4];
            float c  = sigf(gi) * tanh_fast(gu) + sigf(gl) * cl + sigf(gr) * cr;
            float h  = sigf(go) * tanh_fast(c);
            int oi = id * DM + ucol;
            acts[oi]      = h;
            mem[oi]       = c;
            actsb_out[oi] = (bf16)h;
        }
    }
}

extern "C" void kernel_launch(void* const* d_in, const int* in_sizes, int n_in,
                              void* d_out, int out_size, void* d_ws, size_t ws_size,
                              hipStream_t stream) {
    (void)in_sizes; (void)n_in; (void)out_size; (void)ws_size;
    const int*   tokens = (const int*)d_in[0];
    const float* emb    = (const float*)d_in[8];
    const float* W      = (const float*)d_in[9];
    const float* bias   = (const float*)d_in[10];
    float* acts = (float*)d_out;

    char* ws = (char*)d_ws;
    bf16*  Wt    = (bf16*)ws;                               // 1,310,720 B
    bf16*  actsb = (bf16*)(ws + 1310720);                   // 33,546,240 B
    float* mem   = (float*)(ws + 1310720 + 33546240);       // 67,092,480 B

    prep_wt<<<dim3(512 * 1280 / 256), dim3(256), 0, stream>>>(W, Wt);
    leaf_kernel<<<dim3(8192), dim3(256), 0, stream>>>(tokens, emb, acts, actsb);

    int off_km1 = 0;
    for (int k = 1; k <= DEPTH; ++k) {
        int shift   = DEPTH - k;
        int Mt      = 1 << shift;            // rows per tree at this level
        int off_k   = off_km1 + (Mt << 1);
        int M_total = NTREES << shift;
        if (Mt >= 128) {
            level_big<<<dim3((Mt >> 7) * 8, NTREES), dim3(256), 0, stream>>>(
                actsb, Wt, bias, mem, acts, actsb, off_k, off_km1, (k == 1) ? 1 : 0);
        } else if (M_total >= 64) {
            level_kernel64<<<dim3(M_total / 16), dim3(256), 0, stream>>>(
                actsb, Wt, bias, mem, acts, actsb, off_k, off_km1, shift);
        } else {
            level_kernel<<<dim3(M_total / 4), dim3(256), 0, stream>>>(
                actsb, Wt, bias, mem, acts, actsb, off_k, off_km1, shift);
        }
        off_km1 = off_k;
    }
}